// Round 1
// baseline (543.399 us; speedup 1.0000x reference)
//
#include <hip/hip_runtime.h>
#include <hip/hip_bf16.h>

#define NHID 128
#define NGRAPH 512
#define NCLS 10

typedef __attribute__((ext_vector_type(8))) short bf16x8;
typedef __attribute__((ext_vector_type(4))) float f32x4;

// order-preserving float<->uint encoding for atomicMax-based segment max
__device__ inline unsigned int fenc(float f) {
    unsigned int u = __float_as_uint(f);
    return (u & 0x80000000u) ? ~u : (u | 0x80000000u);
}
__device__ inline float fdec(unsigned int u) {
    u = (u & 0x80000000u) ? (u & 0x7fffffffu) : ~u;
    return __uint_as_float(u);
}
// f32 -> bf16 round-to-nearest-even (finite inputs)
__device__ inline unsigned short f2bf(float f) {
    unsigned int u = __float_as_uint(f);
    return (unsigned short)((u + 0x7fffu + ((u >> 16) & 1u)) >> 16);
}

__global__ void k_deg(const int* __restrict__ dst, int* __restrict__ cnt, int E) {
    int e = blockIdx.x * blockDim.x + threadIdx.x;
    if (e < E) atomicAdd(&cnt[dst[e]], 1);
}

__global__ void k_dinv(const int* __restrict__ cnt, float* __restrict__ dinv, int N) {
    int i = blockIdx.x * blockDim.x + threadIdx.x;
    if (i < N) dinv[i] = rsqrtf((float)cnt[i] + 1.0f);
}

// single-block exclusive scan of cnt -> rowptr (N up to ~1e5: 1024-wide chunks)
__global__ __launch_bounds__(1024) void k_scan(const int* __restrict__ cnt,
                                               int* __restrict__ rowptr, int N) {
    __shared__ int lds[1024];
    __shared__ int carry;
    int t = threadIdx.x;
    if (t == 0) { carry = 0; rowptr[0] = 0; }
    __syncthreads();
    for (int base = 0; base < N; base += 1024) {
        int i = base + t;
        int v = (i < N) ? cnt[i] : 0;
        lds[t] = v;
        __syncthreads();
        for (int off = 1; off < 1024; off <<= 1) {
            int x = (t >= off) ? lds[t - off] : 0;
            __syncthreads();
            lds[t] += x;
            __syncthreads();
        }
        int c = carry;
        if (i < N) rowptr[i + 1] = c + lds[t];
        int tot = lds[1023];
        __syncthreads();
        if (t == 0) carry = c + tot;
        __syncthreads();
    }
}

__global__ void k_fill(const int* __restrict__ src, const int* __restrict__ dst,
                       const float* __restrict__ dinv, const int* __restrict__ rowptr,
                       int* __restrict__ cursor, int* __restrict__ csr_src,
                       float* __restrict__ csr_nrm, int E) {
    int e = blockIdx.x * blockDim.x + threadIdx.x;
    if (e >= E) return;
    int s = src[e], d = dst[e];
    int pos = rowptr[d] + atomicAdd(&cursor[d], 1);
    csr_src[pos] = s;
    csr_nrm[pos] = dinv[s] * dinv[d];
}

// one wave per node: agg[i,:] = sum_e norm_e * Hin[src_e,:] + dinv[i]^2 * Hin[i,:]
__global__ __launch_bounds__(256) void k_agg(const float* __restrict__ Hin,
        const int* __restrict__ rowptr, const int* __restrict__ csr_src,
        const float* __restrict__ csr_nrm, const float* __restrict__ dinv,
        float* __restrict__ agg, int N) {
    int w = (blockIdx.x * 256 + threadIdx.x) >> 6;
    if (w >= N) return;
    int lane = threadIdx.x & 63;
    int c0 = lane * 2;
    float a0 = 0.f, a1 = 0.f;
    int beg = rowptr[w], end = rowptr[w + 1];
    for (int j = beg; j < end; ++j) {
        int s = csr_src[j];
        float nw = csr_nrm[j];
        const float* p = Hin + (size_t)s * NHID + c0;
        a0 = fmaf(nw, p[0], a0);
        a1 = fmaf(nw, p[1], a1);
    }
    float di = dinv[w];
    const float* p = Hin + (size_t)w * NHID + c0;
    a0 = fmaf(di * di, p[0], a0);
    a1 = fmaf(di * di, p[1], a1);
    float* q = agg + (size_t)w * NHID + c0;
    q[0] = a0; q[1] = a1;
}

// transpose W [128x128] f32 -> Wt [c][k] bf16
__global__ void k_wt(const float* __restrict__ W, unsigned short* __restrict__ Wt) {
    int idx = blockIdx.x * 256 + threadIdx.x;   // 16384
    int c = idx & 127, k = idx >> 7;
    Wt[c * NHID + k] = f2bf(W[k * NHID + c]);
}

// Hout = relu(A @ W + b); A f32 [M,128] converted to bf16 in-reg; Wt bf16 [c][k]
__global__ __launch_bounds__(256) void k_gemm(const float* __restrict__ A,
        const unsigned short* __restrict__ Wt, const float* __restrict__ bias,
        float* __restrict__ Hout, int M) {
    int wave = threadIdx.x >> 6;
    int lane = threadIdx.x & 63;
    int lr = lane & 15;           // A-row / B-col / D-col within tile
    int kq = lane >> 4;           // k subgroup
    int r0 = blockIdx.x * 64 + wave * 16;
    f32x4 acc[8];
#pragma unroll
    for (int nt = 0; nt < 8; ++nt) acc[nt] = 0.f;
    int ar = r0 + lr;
    bool arok = ar < M;
#pragma unroll
    for (int kg = 0; kg < 4; ++kg) {
        int kb = kg * 32 + kq * 8;
        f32x4 a0 = 0.f, a1 = 0.f;
        if (arok) {
            const float* ap = A + (size_t)ar * NHID + kb;
            a0 = *reinterpret_cast<const f32x4*>(ap);
            a1 = *reinterpret_cast<const f32x4*>(ap + 4);
        }
        union { bf16x8 v; unsigned short h[8]; } af;
#pragma unroll
        for (int e = 0; e < 4; ++e) {
            af.h[e]     = f2bf(a0[e]);
            af.h[e + 4] = f2bf(a1[e]);
        }
#pragma unroll
        for (int nt = 0; nt < 8; ++nt) {
            bf16x8 bf = *reinterpret_cast<const bf16x8*>(Wt + (size_t)(nt * 16 + lr) * NHID + kb);
            acc[nt] = __builtin_amdgcn_mfma_f32_16x16x32_bf16(af.v, bf, acc[nt], 0, 0, 0);
        }
    }
#pragma unroll
    for (int nt = 0; nt < 8; ++nt) {
        int c = nt * 16 + lr;
        float b = bias[c];
#pragma unroll
        for (int e = 0; e < 4; ++e) {
            int r = r0 + kq * 4 + e;
            if (r < M) {
                float v = acc[nt][e] + b;
                Hout[(size_t)r * NHID + c] = fmaxf(v, 0.f);
            }
        }
    }
}

// BN (eval) + segment-max over sorted batch via encoded atomicMax
__global__ __launch_bounds__(256) void k_bnmax(const float* __restrict__ H,
        const int* __restrict__ batch, const float* __restrict__ gamma,
        const float* __restrict__ beta, const float* __restrict__ rmean,
        const float* __restrict__ rvar, unsigned int* __restrict__ keys, int N) {
    int c = threadIdx.x & 127;
    int h = threadIdx.x >> 7;     // 0..1
    int n0 = blockIdx.x * 64;
    float sc = gamma[c] * rsqrtf(rvar[c] + 1e-5f);
    float sh = beta[c] - rmean[c] * sc;
    int cur = -1;
    float m = -3.0e38f;
    int nend = n0 + 64 < N ? n0 + 64 : N;
    for (int n = n0 + h; n < nend; n += 2) {
        int g = batch[n];
        if (g != cur) {
            if (cur >= 0) atomicMax(&keys[(size_t)cur * NHID + c], fenc(m));
            cur = g;
            m = -3.0e38f;
        }
        float y = fmaf(H[(size_t)n * NHID + c], sc, sh);
        m = fmaxf(m, y);
    }
    if (cur >= 0) atomicMax(&keys[(size_t)cur * NHID + c], fenc(m));
}

__global__ void k_decode(const unsigned int* __restrict__ keys, float* __restrict__ G, int n) {
    int i = blockIdx.x * blockDim.x + threadIdx.x;
    if (i < n) {
        unsigned int u = keys[i];
        G[i] = (u == 0u) ? -3.0e38f : fdec(u);
    }
}

// small dense layer: Y[rows,Nc] = (relu?) X[rows,K] @ W[K,Nc] + b
__global__ void k_mlp(const float* __restrict__ X, const float* __restrict__ W,
                      const float* __restrict__ b, float* __restrict__ Y,
                      int rows, int K, int Nc, int relu) {
    int idx = blockIdx.x * blockDim.x + threadIdx.x;
    if (idx >= rows * Nc) return;
    int r = idx / Nc, c = idx % Nc;
    float acc = b[c];
    for (int k = 0; k < K; ++k) acc = fmaf(X[r * K + k], W[k * Nc + c], acc);
    Y[idx] = relu ? fmaxf(acc, 0.f) : acc;
}

extern "C" void kernel_launch(void* const* d_in, const int* in_sizes, int n_in,
                              void* d_out, int out_size, void* d_ws, size_t ws_size,
                              hipStream_t stream) {
    const float* x     = (const float*)d_in[0];
    const int*   ei    = (const int*)d_in[1];
    const int*   batch = (const int*)d_in[2];
    const float* W1 = (const float*)d_in[3];
    const float* b1 = (const float*)d_in[4];
    const float* W2 = (const float*)d_in[5];
    const float* b2 = (const float*)d_in[6];
    const float* W3 = (const float*)d_in[7];
    const float* b3 = (const float*)d_in[8];
    const float* gamma = (const float*)d_in[9];
    const float* beta  = (const float*)d_in[10];
    const float* rmean = (const float*)d_in[11];
    const float* rvar  = (const float*)d_in[12];
    const float* lw1 = (const float*)d_in[13];
    const float* lb1 = (const float*)d_in[14];
    const float* lw2 = (const float*)d_in[15];
    const float* lb2 = (const float*)d_in[16];
    const float* lw3 = (const float*)d_in[17];
    const float* lb3 = (const float*)d_in[18];

    const int N = in_sizes[2];
    const int E = in_sizes[1] / 2;
    const int* src = ei;
    const int* dst = ei + E;

    char* ws = (char*)d_ws;
    size_t off = 0;
    auto alloc = [&](size_t bytes) {
        char* p = ws + off;
        off += (bytes + 255) & ~(size_t)255;
        return p;
    };
    int*   cnt     = (int*)  alloc((size_t)N * 4);
    int*   rowptr  = (int*)  alloc(((size_t)N + 1) * 4);
    int*   cursor  = (int*)  alloc((size_t)N * 4);
    float* dinv    = (float*)alloc((size_t)N * 4);
    int*   csr_src = (int*)  alloc((size_t)E * 4);
    float* csr_nrm = (float*)alloc((size_t)E * 4);
    float* agg     = (float*)alloc((size_t)N * NHID * 4);
    float* H       = (float*)alloc((size_t)N * NHID * 4);
    unsigned short* Wt = (unsigned short*)alloc((size_t)NHID * NHID * 2);
    unsigned int* keys = (unsigned int*)alloc((size_t)NGRAPH * NHID * 4);
    float* G  = (float*)alloc((size_t)NGRAPH * NHID * 4);
    float* g1 = (float*)alloc((size_t)NGRAPH * NHID * 4);
    float* g2 = (float*)alloc((size_t)NGRAPH * (NHID / 2) * 4);
    (void)ws_size; (void)n_in; (void)out_size;

    hipMemsetAsync(cnt, 0, (size_t)N * 4, stream);
    hipMemsetAsync(cursor, 0, (size_t)N * 4, stream);
    hipMemsetAsync(keys, 0, (size_t)NGRAPH * NHID * 4, stream);

    int eb = (E + 255) / 256;
    int nb = (N + 255) / 256;
    k_deg<<<eb, 256, 0, stream>>>(dst, cnt, E);
    k_dinv<<<nb, 256, 0, stream>>>(cnt, dinv, N);
    k_scan<<<1, 1024, 0, stream>>>(cnt, rowptr, N);
    k_fill<<<eb, 256, 0, stream>>>(src, dst, dinv, rowptr, cursor, csr_src, csr_nrm, E);

    int ab = ((size_t)N * 64 + 255) / 256;   // one wave per node
    int gb = (N + 63) / 64;
    const float* Ws[3] = {W1, W2, W3};
    const float* bs[3] = {b1, b2, b3};
    for (int l = 0; l < 3; ++l) {
        k_wt<<<64, 256, 0, stream>>>(Ws[l], Wt);
        k_agg<<<ab, 256, 0, stream>>>(l == 0 ? x : H, rowptr, csr_src, csr_nrm, dinv, agg, N);
        k_gemm<<<gb, 256, 0, stream>>>(agg, Wt, bs[l], H, N);
    }
    k_bnmax<<<gb, 256, 0, stream>>>(H, batch, gamma, beta, rmean, rvar, keys, N);

    int gm = NGRAPH * NHID;
    k_decode<<<(gm + 255) / 256, 256, 0, stream>>>(keys, G, gm);
    k_mlp<<<(gm + 255) / 256, 256, 0, stream>>>(G, lw1, lb1, g1, NGRAPH, NHID, NHID, 1);
    k_mlp<<<(NGRAPH * 64 + 255) / 256, 256, 0, stream>>>(g1, lw2, lb2, g2, NGRAPH, NHID, 64, 1);
    k_mlp<<<(NGRAPH * NCLS + 255) / 256, 256, 0, stream>>>(g2, lw3, lb3, (float*)d_out, NGRAPH, 64, NCLS, 0);
}

// Round 2
// 380.549 us; speedup vs baseline: 1.4279x; 1.4279x over previous
//
#include <hip/hip_runtime.h>
#include <hip/hip_bf16.h>

#define NHID 128
#define NGRAPH 512
#define NCLS 10

typedef __attribute__((ext_vector_type(8))) short bf16x8;
typedef __attribute__((ext_vector_type(4))) float f32x4;

// order-preserving float<->uint encoding for atomicMax-based segment max
__device__ inline unsigned int fenc(float f) {
    unsigned int u = __float_as_uint(f);
    return (u & 0x80000000u) ? ~u : (u | 0x80000000u);
}
__device__ inline float fdec(unsigned int u) {
    u = (u & 0x80000000u) ? (u & 0x7fffffffu) : ~u;
    return __uint_as_float(u);
}
// f32 -> bf16 round-to-nearest-even (finite inputs)
__device__ inline unsigned short f2bf(float f) {
    unsigned int u = __float_as_uint(f);
    return (unsigned short)((u + 0x7fffu + ((u >> 16) & 1u)) >> 16);
}

__global__ void k_deg(const int* __restrict__ dst, int* __restrict__ cnt, int E) {
    int e = blockIdx.x * blockDim.x + threadIdx.x;
    if (e < E) atomicAdd(&cnt[dst[e]], 1);
}

// phase 1: per-block (1024-wide) inclusive scan of cnt into rowptr[i+1],
// block totals into bsum, and dinv as a free rider.
__global__ __launch_bounds__(1024) void k_scan1(const int* __restrict__ cnt,
        float* __restrict__ dinv, int* __restrict__ rowptr,
        int* __restrict__ bsum, int N) {
    __shared__ int lds[1024];
    int t = threadIdx.x;
    int i = blockIdx.x * 1024 + t;
    int v = (i < N) ? cnt[i] : 0;
    if (i < N) dinv[i] = rsqrtf((float)v + 1.0f);
    lds[t] = v;
    __syncthreads();
    for (int off = 1; off < 1024; off <<= 1) {
        int x = (t >= off) ? lds[t - off] : 0;
        __syncthreads();
        lds[t] += x;
        __syncthreads();
    }
    if (i < N) rowptr[i + 1] = lds[t];
    if (t == 1023) bsum[blockIdx.x] = lds[1023];
}

// phase 2: exclusive scan of nb block sums (nb <= 1024), in place
__global__ __launch_bounds__(1024) void k_scan2(int* __restrict__ bsum, int nb) {
    __shared__ int lds[1024];
    int t = threadIdx.x;
    int v = (t < nb) ? bsum[t] : 0;
    lds[t] = v;
    __syncthreads();
    for (int off = 1; off < 1024; off <<= 1) {
        int x = (t >= off) ? lds[t - off] : 0;
        __syncthreads();
        lds[t] += x;
        __syncthreads();
    }
    if (t < nb) bsum[t] = lds[t] - v;
}

// phase 3: add block offsets; rowptr[0]=0
__global__ void k_scan3(int* __restrict__ rowptr, const int* __restrict__ bsum, int N) {
    int i = blockIdx.x * 256 + threadIdx.x;
    if (i < N) rowptr[i + 1] += bsum[i >> 10];
    if (i == 0) rowptr[0] = 0;
}

__global__ void k_fill(const int* __restrict__ src, const int* __restrict__ dst,
                       const float* __restrict__ dinv, const int* __restrict__ rowptr,
                       int* __restrict__ cursor, int* __restrict__ csr_src,
                       float* __restrict__ csr_nrm, int E) {
    int e = blockIdx.x * blockDim.x + threadIdx.x;
    if (e >= E) return;
    int s = src[e], d = dst[e];
    int pos = rowptr[d] + atomicAdd(&cursor[d], 1);
    csr_src[pos] = s;
    csr_nrm[pos] = dinv[s] * dinv[d];
}

// one wave per node: agg[i,:] = sum_e norm_e * Hin[src_e,:] + dinv[i]^2 * Hin[i,:]
// BF=0: f32 input rows; BF=1: bf16 input rows (half the gather bytes)
template <int BF>
__global__ __launch_bounds__(256) void k_agg(const void* __restrict__ Hin_,
        const int* __restrict__ rowptr, const int* __restrict__ csr_src,
        const float* __restrict__ csr_nrm, const float* __restrict__ dinv,
        float* __restrict__ agg, int N) {
    int w = (blockIdx.x * 256 + threadIdx.x) >> 6;
    if (w >= N) return;
    int lane = threadIdx.x & 63;
    int c0 = lane * 2;
    float a0 = 0.f, a1 = 0.f;
    int beg = rowptr[w], end = rowptr[w + 1];
    if (BF) {
        const unsigned int* Hb = (const unsigned int*)Hin_;   // 2 bf16 per u32
        for (int j = beg; j < end; ++j) {
            int s = csr_src[j];
            float nw = csr_nrm[j];
            unsigned int u = Hb[(size_t)s * (NHID / 2) + lane];
            a0 = fmaf(nw, __uint_as_float(u << 16), a0);
            a1 = fmaf(nw, __uint_as_float(u & 0xffff0000u), a1);
        }
        float di = dinv[w];
        unsigned int u = Hb[(size_t)w * (NHID / 2) + lane];
        a0 = fmaf(di * di, __uint_as_float(u << 16), a0);
        a1 = fmaf(di * di, __uint_as_float(u & 0xffff0000u), a1);
    } else {
        const float* Hf = (const float*)Hin_;
        for (int j = beg; j < end; ++j) {
            int s = csr_src[j];
            float nw = csr_nrm[j];
            const float* p = Hf + (size_t)s * NHID + c0;
            a0 = fmaf(nw, p[0], a0);
            a1 = fmaf(nw, p[1], a1);
        }
        float di = dinv[w];
        const float* p = Hf + (size_t)w * NHID + c0;
        a0 = fmaf(di * di, p[0], a0);
        a1 = fmaf(di * di, p[1], a1);
    }
    float* q = agg + (size_t)w * NHID + c0;
    q[0] = a0; q[1] = a1;
}

// transpose all three W [128x128] f32 -> Wt[l] [c][k] bf16
__global__ void k_wt3(const float* __restrict__ W1, const float* __restrict__ W2,
                      const float* __restrict__ W3, unsigned short* __restrict__ Wt) {
    int idx = blockIdx.x * 256 + threadIdx.x;   // 3*16384
    int l = idx >> 14;
    int r = idx & 16383;
    const float* W = (l == 0) ? W1 : (l == 1) ? W2 : W3;
    int c = r & 127, k = r >> 7;
    Wt[l * 16384 + c * NHID + k] = f2bf(W[k * NHID + c]);
}

// Hout = relu(A @ W + b); A f32 [M,128] converted to bf16 in-reg; Wt bf16 [c][k]
// OUTBF=1: write bf16 rows (feeds next k_agg); OUTBF=0: write f32 (feeds bnmax)
template <int OUTBF>
__global__ __launch_bounds__(256) void k_gemm(const float* __restrict__ A,
        const unsigned short* __restrict__ Wt, const float* __restrict__ bias,
        float* __restrict__ Hf, unsigned short* __restrict__ Hb, int M) {
    int wave = threadIdx.x >> 6;
    int lane = threadIdx.x & 63;
    int lr = lane & 15;           // A-row / B-col / D-col within tile
    int kq = lane >> 4;           // k subgroup
    int r0 = blockIdx.x * 64 + wave * 16;
    f32x4 acc[8];
#pragma unroll
    for (int nt = 0; nt < 8; ++nt) acc[nt] = 0.f;
    int ar = r0 + lr;
    bool arok = ar < M;
#pragma unroll
    for (int kg = 0; kg < 4; ++kg) {
        int kb = kg * 32 + kq * 8;
        f32x4 a0 = 0.f, a1 = 0.f;
        if (arok) {
            const float* ap = A + (size_t)ar * NHID + kb;
            a0 = *reinterpret_cast<const f32x4*>(ap);
            a1 = *reinterpret_cast<const f32x4*>(ap + 4);
        }
        union { bf16x8 v; unsigned short h[8]; } af;
#pragma unroll
        for (int e = 0; e < 4; ++e) {
            af.h[e]     = f2bf(a0[e]);
            af.h[e + 4] = f2bf(a1[e]);
        }
#pragma unroll
        for (int nt = 0; nt < 8; ++nt) {
            bf16x8 bf = *reinterpret_cast<const bf16x8*>(Wt + (size_t)(nt * 16 + lr) * NHID + kb);
            acc[nt] = __builtin_amdgcn_mfma_f32_16x16x32_bf16(af.v, bf, acc[nt], 0, 0, 0);
        }
    }
#pragma unroll
    for (int nt = 0; nt < 8; ++nt) {
        int c = nt * 16 + lr;
        float b = bias[c];
#pragma unroll
        for (int e = 0; e < 4; ++e) {
            int r = r0 + kq * 4 + e;
            if (r < M) {
                float v = fmaxf(acc[nt][e] + b, 0.f);
                if (OUTBF) Hb[(size_t)r * NHID + c] = f2bf(v);
                else       Hf[(size_t)r * NHID + c] = v;
            }
        }
    }
}

// BN (eval) + segment-max over sorted batch via encoded atomicMax
__global__ __launch_bounds__(256) void k_bnmax(const float* __restrict__ H,
        const int* __restrict__ batch, const float* __restrict__ gamma,
        const float* __restrict__ beta, const float* __restrict__ rmean,
        const float* __restrict__ rvar, unsigned int* __restrict__ keys, int N) {
    int c = threadIdx.x & 127;
    int h = threadIdx.x >> 7;     // 0..1
    int n0 = blockIdx.x * 64;
    float sc = gamma[c] * rsqrtf(rvar[c] + 1e-5f);
    float sh = beta[c] - rmean[c] * sc;
    int cur = -1;
    float m = -3.0e38f;
    int nend = n0 + 64 < N ? n0 + 64 : N;
    for (int n = n0 + h; n < nend; n += 2) {
        int g = batch[n];
        if (g != cur) {
            if (cur >= 0) atomicMax(&keys[(size_t)cur * NHID + c], fenc(m));
            cur = g;
            m = -3.0e38f;
        }
        float y = fmaf(H[(size_t)n * NHID + c], sc, sh);
        m = fmaxf(m, y);
    }
    if (cur >= 0) atomicMax(&keys[(size_t)cur * NHID + c], fenc(m));
}

// fused head: decode keys -> relu(G@lw1+lb1) -> relu(@lw2+lb2) -> @lw3+lb3
// one block (128 threads) per graph row
__global__ __launch_bounds__(128) void k_head(const unsigned int* __restrict__ keys,
        const float* __restrict__ lw1, const float* __restrict__ lb1,
        const float* __restrict__ lw2, const float* __restrict__ lb2,
        const float* __restrict__ lw3, const float* __restrict__ lb3,
        float* __restrict__ out) {
    __shared__ float g0[NHID], g1[NHID], g2[64];
    int r = blockIdx.x;
    int t = threadIdx.x;
    unsigned int u = keys[(size_t)r * NHID + t];
    g0[t] = (u == 0u) ? -3.0e38f : fdec(u);
    __syncthreads();
    float acc = lb1[t];
#pragma unroll 8
    for (int k = 0; k < NHID; ++k) acc = fmaf(g0[k], lw1[k * NHID + t], acc);
    g1[t] = fmaxf(acc, 0.f);
    __syncthreads();
    if (t < 64) {
        acc = lb2[t];
#pragma unroll 8
        for (int k = 0; k < NHID; ++k) acc = fmaf(g1[k], lw2[k * 64 + t], acc);
        g2[t] = fmaxf(acc, 0.f);
    }
    __syncthreads();
    if (t < NCLS) {
        acc = lb3[t];
#pragma unroll 8
        for (int k = 0; k < 64; ++k) acc = fmaf(g2[k], lw3[k * NCLS + t], acc);
        out[(size_t)r * NCLS + t] = acc;
    }
}

extern "C" void kernel_launch(void* const* d_in, const int* in_sizes, int n_in,
                              void* d_out, int out_size, void* d_ws, size_t ws_size,
                              hipStream_t stream) {
    const float* x     = (const float*)d_in[0];
    const int*   ei    = (const int*)d_in[1];
    const int*   batch = (const int*)d_in[2];
    const float* W1 = (const float*)d_in[3];
    const float* b1 = (const float*)d_in[4];
    const float* W2 = (const float*)d_in[5];
    const float* b2 = (const float*)d_in[6];
    const float* W3 = (const float*)d_in[7];
    const float* b3 = (const float*)d_in[8];
    const float* gamma = (const float*)d_in[9];
    const float* beta  = (const float*)d_in[10];
    const float* rmean = (const float*)d_in[11];
    const float* rvar  = (const float*)d_in[12];
    const float* lw1 = (const float*)d_in[13];
    const float* lb1 = (const float*)d_in[14];
    const float* lw2 = (const float*)d_in[15];
    const float* lb2 = (const float*)d_in[16];
    const float* lw3 = (const float*)d_in[17];
    const float* lb3 = (const float*)d_in[18];

    const int N = in_sizes[2];
    const int E = in_sizes[1] / 2;
    const int* src = ei;
    const int* dst = ei + E;

    char* ws = (char*)d_ws;
    size_t off = 0;
    auto alloc = [&](size_t bytes) {
        char* p = ws + off;
        off += (bytes + 255) & ~(size_t)255;
        return p;
    };
    int*   cnt     = (int*)  alloc((size_t)N * 8);     // cnt[N] + cursor[N], one memset
    int*   cursor  = cnt + N;
    int*   rowptr  = (int*)  alloc(((size_t)N + 1) * 4);
    int*   bsum    = (int*)  alloc(1024 * 4);
    float* dinv    = (float*)alloc((size_t)N * 4);
    int*   csr_src = (int*)  alloc((size_t)E * 4);
    float* csr_nrm = (float*)alloc((size_t)E * 4);
    float* agg     = (float*)alloc((size_t)N * NHID * 4);
    float* H       = (float*)alloc((size_t)N * NHID * 4);
    unsigned short* Hb = (unsigned short*)alloc((size_t)N * NHID * 2);
    unsigned short* Wt = (unsigned short*)alloc((size_t)3 * NHID * NHID * 2);
    unsigned int* keys = (unsigned int*)alloc((size_t)NGRAPH * NHID * 4);
    (void)ws_size; (void)n_in; (void)out_size;

    hipMemsetAsync(cnt, 0, (size_t)N * 8, stream);
    hipMemsetAsync(keys, 0, (size_t)NGRAPH * NHID * 4, stream);

    int eb = (E + 255) / 256;
    int nb1 = (N + 1023) / 1024;
    k_deg<<<eb, 256, 0, stream>>>(dst, cnt, E);
    k_scan1<<<nb1, 1024, 0, stream>>>(cnt, dinv, rowptr, bsum, N);
    k_scan2<<<1, 1024, 0, stream>>>(bsum, nb1);
    k_scan3<<<(N + 255) / 256, 256, 0, stream>>>(rowptr, bsum, N);
    k_fill<<<eb, 256, 0, stream>>>(src, dst, dinv, rowptr, cursor, csr_src, csr_nrm, E);
    k_wt3<<<192, 256, 0, stream>>>(W1, W2, W3, Wt);

    int ab = ((size_t)N * 64 + 255) / 256;   // one wave per node
    int gb = (N + 63) / 64;
    // layer 1: f32 x -> bf16 H
    k_agg<0><<<ab, 256, 0, stream>>>(x, rowptr, csr_src, csr_nrm, dinv, agg, N);
    k_gemm<1><<<gb, 256, 0, stream>>>(agg, Wt, b1, nullptr, Hb, N);
    // layer 2: bf16 H -> bf16 H (in-place safe: gemm only writes, reads agg)
    k_agg<1><<<ab, 256, 0, stream>>>(Hb, rowptr, csr_src, csr_nrm, dinv, agg, N);
    k_gemm<1><<<gb, 256, 0, stream>>>(agg, Wt + 16384, b2, nullptr, Hb, N);
    // layer 3: bf16 H -> f32 H (feeds bnmax)
    k_agg<1><<<ab, 256, 0, stream>>>(Hb, rowptr, csr_src, csr_nrm, dinv, agg, N);
    k_gemm<0><<<gb, 256, 0, stream>>>(agg, Wt + 32768, b3, H, nullptr, N);

    k_bnmax<<<gb, 256, 0, stream>>>(H, batch, gamma, beta, rmean, rvar, keys, N);
    k_head<<<NGRAPH, 128, 0, stream>>>(keys, lw1, lb1, lw2, lb2, lw3, lb3, (float*)d_out);
}

// Round 3
// 282.953 us; speedup vs baseline: 1.9205x; 1.3449x over previous
//
#include <hip/hip_runtime.h>
#include <hip/hip_bf16.h>

#define NHID 128
#define NGRAPH 512
#define NCLS 10

typedef __attribute__((ext_vector_type(8))) short bf16x8;
typedef __attribute__((ext_vector_type(4))) float f32x4;
typedef __attribute__((ext_vector_type(4))) unsigned int u32x4;

// order-preserving float<->uint encoding for atomicMax-based segment max
__device__ inline unsigned int fenc(float f) {
    unsigned int u = __float_as_uint(f);
    return (u & 0x80000000u) ? ~u : (u | 0x80000000u);
}
__device__ inline float fdec(unsigned int u) {
    u = (u & 0x80000000u) ? (u & 0x7fffffffu) : ~u;
    return __uint_as_float(u);
}
// f32 -> bf16 round-to-nearest-even (finite inputs)
__device__ inline unsigned short f2bf(float f) {
    unsigned int u = __float_as_uint(f);
    return (unsigned short)((u + 0x7fffu + ((u >> 16) & 1u)) >> 16);
}

__global__ void k_deg(const int* __restrict__ dst, int* __restrict__ cnt, int E) {
    int e = blockIdx.x * blockDim.x + threadIdx.x;
    if (e < E) atomicAdd(&cnt[dst[e]], 1);
}

// phase 1: per-block (1024-wide) inclusive scan of cnt into rowptr[i+1],
// block totals into bsum, and dinv as a free rider.
__global__ __launch_bounds__(1024) void k_scan1(const int* __restrict__ cnt,
        float* __restrict__ dinv, int* __restrict__ rowptr,
        int* __restrict__ bsum, int N) {
    __shared__ int lds[1024];
    int t = threadIdx.x;
    int i = blockIdx.x * 1024 + t;
    int v = (i < N) ? cnt[i] : 0;
    if (i < N) dinv[i] = rsqrtf((float)v + 1.0f);
    lds[t] = v;
    __syncthreads();
    for (int off = 1; off < 1024; off <<= 1) {
        int x = (t >= off) ? lds[t - off] : 0;
        __syncthreads();
        lds[t] += x;
        __syncthreads();
    }
    if (i < N) rowptr[i + 1] = lds[t];
    if (t == 1023) bsum[blockIdx.x] = lds[1023];
}

// phase 2: exclusive scan of nb block sums (nb <= 1024), in place
__global__ __launch_bounds__(1024) void k_scan2(int* __restrict__ bsum, int nb) {
    __shared__ int lds[1024];
    int t = threadIdx.x;
    int v = (t < nb) ? bsum[t] : 0;
    lds[t] = v;
    __syncthreads();
    for (int off = 1; off < 1024; off <<= 1) {
        int x = (t >= off) ? lds[t - off] : 0;
        __syncthreads();
        lds[t] += x;
        __syncthreads();
    }
    if (t < nb) bsum[t] = lds[t] - v;
}

// phase 3: add block offsets; rowptr[0]=0
__global__ void k_scan3(int* __restrict__ rowptr, const int* __restrict__ bsum, int N) {
    int i = blockIdx.x * 256 + threadIdx.x;
    if (i < N) rowptr[i + 1] += bsum[i >> 10];
    if (i == 0) rowptr[0] = 0;
}

__global__ void k_fill(const int* __restrict__ src, const int* __restrict__ dst,
                       const float* __restrict__ dinv, const int* __restrict__ rowptr,
                       int* __restrict__ cursor, int* __restrict__ csr_src,
                       float* __restrict__ csr_nrm, int E) {
    int e = blockIdx.x * blockDim.x + threadIdx.x;
    if (e >= E) return;
    int s = src[e], d = dst[e];
    int pos = rowptr[d] + atomicAdd(&cursor[d], 1);
    csr_src[pos] = s;
    csr_nrm[pos] = dinv[s] * dinv[d];
}

// x f32 [N,128] -> bf16 (each thread converts 8 elements)
__global__ void k_xbf(const float* __restrict__ x, unsigned int* __restrict__ xb, int n8) {
    int i = blockIdx.x * 256 + threadIdx.x;
    if (i >= n8) return;
    const float* p = x + (size_t)i * 8;
    f32x4 a = *reinterpret_cast<const f32x4*>(p);
    f32x4 b = *reinterpret_cast<const f32x4*>(p + 4);
    u32x4 o;
    o[0] = (unsigned)f2bf(a[0]) | ((unsigned)f2bf(a[1]) << 16);
    o[1] = (unsigned)f2bf(a[2]) | ((unsigned)f2bf(a[3]) << 16);
    o[2] = (unsigned)f2bf(b[0]) | ((unsigned)f2bf(b[1]) << 16);
    o[3] = (unsigned)f2bf(b[2]) | ((unsigned)f2bf(b[3]) << 16);
    *reinterpret_cast<u32x4*>(xb + (size_t)i * 4) = o;
}

__device__ inline void fma8(const u32x4& u, float nw, float* a) {
#pragma unroll
    for (int q = 0; q < 4; ++q) {
        a[2 * q]     = fmaf(nw, __uint_as_float(u[q] << 16), a[2 * q]);
        a[2 * q + 1] = fmaf(nw, __uint_as_float(u[q] & 0xffff0000u), a[2 * q + 1]);
    }
}

// one wave per node, 4 x 16-lane gather groups, bf16 input rows (256B each).
// group g handles edges beg+g, beg+g+4, ...; lane (l16) covers cols l16*8..+8.
// cross-group combine via shfl_xor(16),(32); group 0 adds self-loop and writes.
__global__ __launch_bounds__(256) void k_agg(const unsigned int* __restrict__ Hb,
        const int* __restrict__ rowptr, const int* __restrict__ csr_src,
        const float* __restrict__ csr_nrm, const float* __restrict__ dinv,
        float* __restrict__ agg, int N) {
    int w = (blockIdx.x * 256 + threadIdx.x) >> 6;
    if (w >= N) return;
    int lane = threadIdx.x & 63;
    int g = lane >> 4;        // gather group 0..3
    int l16 = lane & 15;      // 16B chunk within row
    float a[8];
#pragma unroll
    for (int e = 0; e < 8; ++e) a[e] = 0.f;
    int beg = rowptr[w], end = rowptr[w + 1];
    int trips = (end - beg + 3) >> 2;
    int j = beg + g;
#pragma unroll 2
    for (int t = 0; t < trips; ++t, j += 4) {
        int s = w;
        float nw = 0.f;
        if (j < end) { s = csr_src[j]; nw = csr_nrm[j]; }
        u32x4 u = reinterpret_cast<const u32x4*>(Hb + (size_t)s * (NHID / 2))[l16];
        fma8(u, nw, a);
    }
    // self-loop on group 0
    if (g == 0) {
        float di = dinv[w];
        u32x4 u = reinterpret_cast<const u32x4*>(Hb + (size_t)w * (NHID / 2))[l16];
        fma8(u, di * di, a);
    }
    // combine the 4 groups
#pragma unroll
    for (int e = 0; e < 8; ++e) {
        a[e] += __shfl_xor(a[e], 16);
        a[e] += __shfl_xor(a[e], 32);
    }
    if (g == 0) {
        float* q = agg + (size_t)w * NHID + l16 * 8;
        f32x4 v0, v1;
#pragma unroll
        for (int e = 0; e < 4; ++e) { v0[e] = a[e]; v1[e] = a[e + 4]; }
        *reinterpret_cast<f32x4*>(q) = v0;
        *reinterpret_cast<f32x4*>(q + 4) = v1;
    }
}

// transpose all three W [128x128] f32 -> Wt[l] [c][k] bf16
__global__ void k_wt3(const float* __restrict__ W1, const float* __restrict__ W2,
                      const float* __restrict__ W3, unsigned short* __restrict__ Wt) {
    int idx = blockIdx.x * 256 + threadIdx.x;   // 3*16384
    int l = idx >> 14;
    int r = idx & 16383;
    const float* W = (l == 0) ? W1 : (l == 1) ? W2 : W3;
    int c = r & 127, k = r >> 7;
    Wt[l * 16384 + c * NHID + k] = f2bf(W[k * NHID + c]);
}

// Hb_out = relu(A @ W + b) as bf16; A f32 [M,128] converted to bf16 in-reg
__global__ __launch_bounds__(256) void k_gemm(const float* __restrict__ A,
        const unsigned short* __restrict__ Wt, const float* __restrict__ bias,
        unsigned short* __restrict__ Hb, int M) {
    int wave = threadIdx.x >> 6;
    int lane = threadIdx.x & 63;
    int lr = lane & 15;           // A-row / B-col / D-col within tile
    int kq = lane >> 4;           // k subgroup
    int r0 = blockIdx.x * 64 + wave * 16;
    f32x4 acc[8];
#pragma unroll
    for (int nt = 0; nt < 8; ++nt) acc[nt] = 0.f;
    int ar = r0 + lr;
    bool arok = ar < M;
#pragma unroll
    for (int kg = 0; kg < 4; ++kg) {
        int kb = kg * 32 + kq * 8;
        f32x4 a0 = 0.f, a1 = 0.f;
        if (arok) {
            const float* ap = A + (size_t)ar * NHID + kb;
            a0 = *reinterpret_cast<const f32x4*>(ap);
            a1 = *reinterpret_cast<const f32x4*>(ap + 4);
        }
        union { bf16x8 v; unsigned short h[8]; } af;
#pragma unroll
        for (int e = 0; e < 4; ++e) {
            af.h[e]     = f2bf(a0[e]);
            af.h[e + 4] = f2bf(a1[e]);
        }
#pragma unroll
        for (int nt = 0; nt < 8; ++nt) {
            bf16x8 bf = *reinterpret_cast<const bf16x8*>(Wt + (size_t)(nt * 16 + lr) * NHID + kb);
            acc[nt] = __builtin_amdgcn_mfma_f32_16x16x32_bf16(af.v, bf, acc[nt], 0, 0, 0);
        }
    }
#pragma unroll
    for (int nt = 0; nt < 8; ++nt) {
        int c = nt * 16 + lr;
        float b = bias[c];
#pragma unroll
        for (int e = 0; e < 4; ++e) {
            int r = r0 + kq * 4 + e;
            if (r < M) {
                float v = fmaxf(acc[nt][e] + b, 0.f);
                Hb[(size_t)r * NHID + c] = f2bf(v);
            }
        }
    }
}

// BN (eval) + segment-max over sorted batch via encoded atomicMax; bf16 input
__global__ __launch_bounds__(256) void k_bnmax(const unsigned short* __restrict__ Hb,
        const int* __restrict__ batch, const float* __restrict__ gamma,
        const float* __restrict__ beta, const float* __restrict__ rmean,
        const float* __restrict__ rvar, unsigned int* __restrict__ keys, int N) {
    int c = threadIdx.x & 127;
    int h = threadIdx.x >> 7;     // 0..1
    int n0 = blockIdx.x * 64;
    float sc = gamma[c] * rsqrtf(rvar[c] + 1e-5f);
    float sh = beta[c] - rmean[c] * sc;
    int cur = -1;
    float m = -3.0e38f;
    int nend = n0 + 64 < N ? n0 + 64 : N;
    for (int n = n0 + h; n < nend; n += 2) {
        int g = batch[n];
        if (g != cur) {
            if (cur >= 0) atomicMax(&keys[(size_t)cur * NHID + c], fenc(m));
            cur = g;
            m = -3.0e38f;
        }
        float hv = __uint_as_float(((unsigned)Hb[(size_t)n * NHID + c]) << 16);
        float y = fmaf(hv, sc, sh);
        m = fmaxf(m, y);
    }
    if (cur >= 0) atomicMax(&keys[(size_t)cur * NHID + c], fenc(m));
}

// fused head: decode keys -> relu(G@lw1+lb1) -> relu(@lw2+lb2) -> @lw3+lb3
// one block (128 threads) per graph row
__global__ __launch_bounds__(128) void k_head(const unsigned int* __restrict__ keys,
        const float* __restrict__ lw1, const float* __restrict__ lb1,
        const float* __restrict__ lw2, const float* __restrict__ lb2,
        const float* __restrict__ lw3, const float* __restrict__ lb3,
        float* __restrict__ out) {
    __shared__ float g0[NHID], g1[NHID], g2[64];
    int r = blockIdx.x;
    int t = threadIdx.x;
    unsigned int u = keys[(size_t)r * NHID + t];
    g0[t] = (u == 0u) ? -3.0e38f : fdec(u);
    __syncthreads();
    float acc = lb1[t];
#pragma unroll 8
    for (int k = 0; k < NHID; ++k) acc = fmaf(g0[k], lw1[k * NHID + t], acc);
    g1[t] = fmaxf(acc, 0.f);
    __syncthreads();
    if (t < 64) {
        acc = lb2[t];
#pragma unroll 8
        for (int k = 0; k < NHID; ++k) acc = fmaf(g1[k], lw2[k * 64 + t], acc);
        g2[t] = fmaxf(acc, 0.f);
    }
    __syncthreads();
    if (t < NCLS) {
        acc = lb3[t];
#pragma unroll 8
        for (int k = 0; k < 64; ++k) acc = fmaf(g2[k], lw3[k * NCLS + t], acc);
        out[(size_t)r * NCLS + t] = acc;
    }
}

extern "C" void kernel_launch(void* const* d_in, const int* in_sizes, int n_in,
                              void* d_out, int out_size, void* d_ws, size_t ws_size,
                              hipStream_t stream) {
    const float* x     = (const float*)d_in[0];
    const int*   ei    = (const int*)d_in[1];
    const int*   batch = (const int*)d_in[2];
    const float* W1 = (const float*)d_in[3];
    const float* b1 = (const float*)d_in[4];
    const float* W2 = (const float*)d_in[5];
    const float* b2 = (const float*)d_in[6];
    const float* W3 = (const float*)d_in[7];
    const float* b3 = (const float*)d_in[8];
    const float* gamma = (const float*)d_in[9];
    const float* beta  = (const float*)d_in[10];
    const float* rmean = (const float*)d_in[11];
    const float* rvar  = (const float*)d_in[12];
    const float* lw1 = (const float*)d_in[13];
    const float* lb1 = (const float*)d_in[14];
    const float* lw2 = (const float*)d_in[15];
    const float* lb2 = (const float*)d_in[16];
    const float* lw3 = (const float*)d_in[17];
    const float* lb3 = (const float*)d_in[18];

    const int N = in_sizes[2];
    const int E = in_sizes[1] / 2;
    const int* src = ei;
    const int* dst = ei + E;

    char* ws = (char*)d_ws;
    size_t off = 0;
    auto alloc = [&](size_t bytes) {
        char* p = ws + off;
        off += (bytes + 255) & ~(size_t)255;
        return p;
    };
    int*   cnt     = (int*)  alloc((size_t)N * 8);     // cnt[N] + cursor[N], one memset
    int*   cursor  = cnt + N;
    int*   rowptr  = (int*)  alloc(((size_t)N + 1) * 4);
    int*   bsum    = (int*)  alloc(1024 * 4);
    float* dinv    = (float*)alloc((size_t)N * 4);
    int*   csr_src = (int*)  alloc((size_t)E * 4);
    float* csr_nrm = (float*)alloc((size_t)E * 4);
    float* agg     = (float*)alloc((size_t)N * NHID * 4);
    unsigned int* xb = (unsigned int*)alloc((size_t)N * NHID * 2);
    unsigned int* Hb = (unsigned int*)alloc((size_t)N * NHID * 2);
    unsigned short* Wt = (unsigned short*)alloc((size_t)3 * NHID * NHID * 2);
    unsigned int* keys = (unsigned int*)alloc((size_t)NGRAPH * NHID * 4);
    (void)ws_size; (void)n_in; (void)out_size;

    hipMemsetAsync(cnt, 0, (size_t)N * 8, stream);
    hipMemsetAsync(keys, 0, (size_t)NGRAPH * NHID * 4, stream);

    int eb = (E + 255) / 256;
    int nb1 = (N + 1023) / 1024;
    k_deg<<<eb, 256, 0, stream>>>(dst, cnt, E);
    k_scan1<<<nb1, 1024, 0, stream>>>(cnt, dinv, rowptr, bsum, N);
    k_scan2<<<1, 1024, 0, stream>>>(bsum, nb1);
    k_scan3<<<(N + 255) / 256, 256, 0, stream>>>(rowptr, bsum, N);
    k_fill<<<eb, 256, 0, stream>>>(src, dst, dinv, rowptr, cursor, csr_src, csr_nrm, E);
    k_wt3<<<192, 256, 0, stream>>>(W1, W2, W3, Wt);
    k_xbf<<<(N * 16 + 255) / 256, 256, 0, stream>>>(x, xb, N * 16);

    int ab = ((size_t)N * 64 + 255) / 256;   // one wave per node
    int gb = (N + 63) / 64;
    k_agg<<<ab, 256, 0, stream>>>(xb, rowptr, csr_src, csr_nrm, dinv, agg, N);
    k_gemm<<<gb, 256, 0, stream>>>(agg, Wt, b1, (unsigned short*)Hb, N);
    k_agg<<<ab, 256, 0, stream>>>(Hb, rowptr, csr_src, csr_nrm, dinv, agg, N);
    k_gemm<<<gb, 256, 0, stream>>>(agg, Wt + 16384, b2, (unsigned short*)Hb, N);
    k_agg<<<ab, 256, 0, stream>>>(Hb, rowptr, csr_src, csr_nrm, dinv, agg, N);
    k_gemm<<<gb, 256, 0, stream>>>(agg, Wt + 32768, b3, (unsigned short*)Hb, N);

    k_bnmax<<<gb, 256, 0, stream>>>((const unsigned short*)Hb, batch, gamma, beta, rmean, rvar, keys, N);
    k_head<<<NGRAPH, 128, 0, stream>>>(keys, lw1, lb1, lw2, lb2, lw3, lb3, (float*)d_out);
}